// Round 9
// baseline (502.831 us; speedup 1.0000x reference)
//
#include <hip/hip_runtime.h>

// Exact-order float32 arithmetic: numpy/jax evaluate left-to-right with no
// FMA contraction. hipcc defaults to -ffp-contract=fast, which would change
// rounding -> possible spike-time shift -> large voltage absmax error.
#pragma clang fp contract(off)

// R22: WHOLE NETWORK IN ONE LANE — no ballot, no SALU resolve, no inline
// asm, no speculation. Ledger R14-R21: the only change that ever helped was
// shortening the serial dependent chain (R18: -2 deps -> -16us, ~4.7ns/dep);
// every scheme that kept (or multiplied) the per-step wave-level ballot ->
// SALU -> VALU round-trip regressed. 5 neurons x (v,u) = 10 floats fit in
// one lane's registers, so the cross-neuron resolve cascade
//   z2 -> I3 -> z3 -> {I4,I5} -> {z4,z5} -> I6 -> z6
// is plain v_cmp (VCC) -> v_cndmask, all in the vector pipe with
// forwarding. Heads (I-independent, 6 ops/neuron) + u-chains of all 5
// neurons are parallel ILP; consecutive steps overlap freely (nothing
// wave-collective inside the loop). Lanes 0-31 compute redundantly
// (identical values); lane 0 stores.
// All f32 op sequences are the validated lineage (R2..R21, absmax 0.0):
//   head: t1=0.04v; t2=t1*v; t3=5v; t4=t2+t3; t5=t4+140; t6=t5-u
//   u:    bv=b*v; bvu=bv-u; du=ka*bvu; u1=u+du; u1d=u1+d
//   tail: t7=t6+I; v1=fmaf(0.25f,t7,v)  [exact: 0.25*x is a pure exponent
//         shift]; fire=(v1>=30); v=fire?c:v1; u=fire?u1d:u1
// with the validated constant-I set (z*w is exactly +0.0f or w).
// Detection: same state as R13 ({v,u} x 5 neurons + carries z2,z4,z5), now
// compared in-lane (13 scalar compares, no ballots). 4-step blocks with a
// mod-10 counter preserve the EXACT rolling-40 cadence (t%40==0 checks) +
// Brent pow-2 coarse anchors (8,16,32,... all multiples of 4). fill_cycle
// copies the periodic continuation (unchanged).

__global__ __launch_bounds__(256) void net_sim(const float* __restrict__ mat,
                                               const float* __restrict__ w,
                                               float* __restrict__ out,
                                               int* __restrict__ ws,
                                               int T) {
    __shared__ double red[256];
    const int tid = threadIdx.x;

    // ---- z_plus = sum(input_mat * w0), f32 products accumulated in f64 ----
    const float w0 = w[0];
    double s = 0.0;
    for (int i = tid; i < 127 * 127; i += 256) {
        float p = mat[i] * w0;   // elementwise product rounded to f32 (as ref)
        s += (double)p;
    }
    red[tid] = s;
    __syncthreads();
    #pragma unroll
    for (int off = 128; off > 0; off >>= 1) {
        if (tid < off) red[tid] += red[tid + off];
        __syncthreads();
    }
    if (tid >= 32) return;   // half-wave of wave 0 continues; no more barriers

    const float z_plus = (float)red[0];

    const float w2 = w[2], w3 = w[3], w5 = w[5], w6 = w[6], w7 = w[7],
                w8 = w[8], w9 = w[9], w10 = w[10], w11 = w[11];
    const float zp_w1 = z_plus * w[1];
    const float zp_w4 = z_plus * w[4];

    // Validated constant-I set (R2..R21, absmax 0.0)
    const float I2_00 = w2 * (zp_w1 - 0.0f) + w3 * 0.0f;   // (z2p, z4p)
    const float I2_10 = w2 * (zp_w1 - 0.0f) + w3 * 1.0f;
    const float I2_01 = w2 * (zp_w1 - w7)   + w3 * 0.0f;
    const float I2_11 = w2 * (zp_w1 - w7)   + w3 * 1.0f;
    const float I3_0  = zp_w4 + 0.0f * w5;
    const float I3_1  = zp_w4 + 1.0f * w5;
    const float I4_0  = 0.0f * w6;
    const float I4_1  = 1.0f * w6;
    const float I5_00 = w9 * (0.0f * w8) + w10 * 0.0f;     // (z3, z5p)
    const float I5_10 = w9 * (1.0f * w8) + w10 * 0.0f;
    const float I5_01 = w9 * (0.0f * w8) + w10 * 1.0f;
    const float I5_11 = w9 * (1.0f * w8) + w10 * 1.0f;
    const float I6_0  = 0.0f * w11;
    const float I6_1  = 1.0f * w11;

    // ka = float(TAU*DT*a) computed in f64 like Python
    const float kaL = (float)(0.25 * 0.1);
    const float kaO = (float)(0.25 * 0.02);

    // network state (one copy per lane, identical across lanes)
    float v2 = -60.0f, u2 = 4.5f;     // LLBN
    float v3 = -64.0f, u3 = -16.0f;   // EBN
    float v4 = -64.0f, u4 = -16.0f;   // IFN
    float v5 = -70.0f, u5 = -14.0f;   // TN
    float v6 = -64.0f, u6 = -16.0f;   // MN
    int z2p = 0, z4p = 0, z5p = 0;    // carries

    // row base pointers (used by lane 0; uniform arithmetic)
    float* p0 = out;           float* q0 = out + 5 * T;
    float* p1 = out + T;       float* q1 = out + 6 * T;
    float* p2 = out + 2 * T;   float* q2 = out + 7 * T;
    float* p3 = out + 3 * T;   float* q3 = out + 8 * T;
    float* p4 = out + 4 * T;   float* q4 = out + 9 * T;

    // ---- cycle-detection: rolling-40 anchor + Brent pow-2 fallback ----
    float rv2=0,ru2=0,rv3=0,ru3=0,rv4=0,ru4=0,rv5=0,ru5=0,rv6=0,ru6=0;
    int rz2=0, rz4=0, rz5=0, ra_t=-1;
    float cv2=0,cu2=0,cv3=0,cu3=0,cv4=0,cu4=0,cv5=0,cu5=0,cv6=0,cu6=0;
    int cz2=0, cz4=0, cz5=0, ca_t=-1;
    int next_coarse = 8;
    int t_det = -1, Pf = 0;
    int blk10 = 0;   // t/4 mod 10; 0 <=> t % 40 == 0

    float zbL[4], zbE[4], zbI[4], zbT[4], zbM[4];
    float vbL[4], vbE[4], vbI[4], vbT[4], vbM[4];

    int t = 0;
    for (; t + 4 <= T; t += 4) {
        // ---- block top: anchor compares / refresh (R9/R13 semantics) ----
        if (blk10 == 0) {
            if (ra_t >= 0) {
                bool eq =
                    (__float_as_uint(v2) == __float_as_uint(rv2)) &&
                    (__float_as_uint(u2) == __float_as_uint(ru2)) &&
                    (__float_as_uint(v3) == __float_as_uint(rv3)) &&
                    (__float_as_uint(u3) == __float_as_uint(ru3)) &&
                    (__float_as_uint(v4) == __float_as_uint(rv4)) &&
                    (__float_as_uint(u4) == __float_as_uint(ru4)) &&
                    (__float_as_uint(v5) == __float_as_uint(rv5)) &&
                    (__float_as_uint(u5) == __float_as_uint(ru5)) &&
                    (__float_as_uint(v6) == __float_as_uint(rv6)) &&
                    (__float_as_uint(u6) == __float_as_uint(ru6)) &&
                    (z2p == rz2) && (z4p == rz4) && (z5p == rz5);
                if (eq) { t_det = t; Pf = t - ra_t; break; }   // Pf == 40
            }
            if (t) {
                rv2=v2; ru2=u2; rv3=v3; ru3=u3; rv4=v4; ru4=u4;
                rv5=v5; ru5=u5; rv6=v6; ru6=u6;
                rz2=z2p; rz4=z4p; rz5=z5p; ra_t=t;
            }
        } else if (ca_t >= 0) {
            bool eq =
                (__float_as_uint(v2) == __float_as_uint(cv2)) &&
                (__float_as_uint(u2) == __float_as_uint(cu2)) &&
                (__float_as_uint(v3) == __float_as_uint(cv3)) &&
                (__float_as_uint(u3) == __float_as_uint(cu3)) &&
                (__float_as_uint(v4) == __float_as_uint(cv4)) &&
                (__float_as_uint(u4) == __float_as_uint(cu4)) &&
                (__float_as_uint(v5) == __float_as_uint(cv5)) &&
                (__float_as_uint(u5) == __float_as_uint(cu5)) &&
                (__float_as_uint(v6) == __float_as_uint(cv6)) &&
                (__float_as_uint(u6) == __float_as_uint(cu6)) &&
                (z2p == cz2) && (z4p == cz4) && (z5p == cz5);
            if (eq) { t_det = t; Pf = t - ca_t; break; }
        }
        if (t == next_coarse) {
            cv2=v2; cu2=u2; cv3=v3; cu3=u3; cv4=v4; cu4=u4;
            cv5=v5; cu5=u5; cv6=v6; cu6=u6;
            cz2=z2p; cz4=z4p; cz5=z5p; ca_t=t;
            next_coarse <<= 1;
        }
        blk10 = (blk10 == 9) ? 0 : (blk10 + 1);

        #pragma unroll
        for (int j = 0; j < 4; ++j) {
            // LLBN (I from carries)
            float I2 = z4p ? (z2p ? I2_11 : I2_01) : (z2p ? I2_10 : I2_00);
            float La1 = 0.04f * v2; float La2 = La1 * v2; float La3 = 5.0f * v2;
            float La4 = La2 + La3;  float La5 = La4 + 140.0f; float La6 = La5 - u2;
            float Lbv = -0.075f * v2; float Lbu = Lbv - u2; float Ldu = kaL * Lbu;
            float Lu1 = u2 + Ldu;   float Lud = Lu1 + 6.0f;
            float Lt7 = La6 + I2;   float Lv1 = fmaf(0.25f, Lt7, v2);
            bool Z2 = (Lv1 >= 30.0f);
            v2 = Z2 ? -55.0f : Lv1;  u2 = Z2 ? Lud : Lu1;

            // EBN (I3 from current z2)
            float I3 = Z2 ? I3_1 : I3_0;
            float Ea1 = 0.04f * v3; float Ea2 = Ea1 * v3; float Ea3 = 5.0f * v3;
            float Ea4 = Ea2 + Ea3;  float Ea5 = Ea4 + 140.0f; float Ea6 = Ea5 - u3;
            float Ebv = 0.25f * v3; float Ebu = Ebv - u3; float Edu = kaO * Ebu;
            float Eu1 = u3 + Edu;   float Eud = Eu1 + 0.05f;
            float Et7 = Ea6 + I3;   float Ev1 = fmaf(0.25f, Et7, v3);
            bool Z3 = (Ev1 >= 30.0f);
            v3 = Z3 ? -55.0f : Ev1;  u3 = Z3 ? Eud : Eu1;

            // IFN (I4 from current z3)
            float I4 = Z3 ? I4_1 : I4_0;
            float Fa1 = 0.04f * v4; float Fa2 = Fa1 * v4; float Fa3 = 5.0f * v4;
            float Fa4 = Fa2 + Fa3;  float Fa5 = Fa4 + 140.0f; float Fa6 = Fa5 - u4;
            float Fbv = 0.25f * v4; float Fbu = Fbv - u4; float Fdu = kaO * Fbu;
            float Fu1 = u4 + Fdu;   float Fud = Fu1 + 6.0f;
            float Ft7 = Fa6 + I4;   float Fv1 = fmaf(0.25f, Ft7, v4);
            bool Z4 = (Fv1 >= 30.0f);
            v4 = Z4 ? -65.0f : Fv1;  u4 = Z4 ? Fud : Fu1;

            // TN (I5 from current z3 and carry z5p)
            float I5 = z5p ? (Z3 ? I5_11 : I5_01) : (Z3 ? I5_10 : I5_00);
            float Ta1 = 0.04f * v5; float Ta2 = Ta1 * v5; float Ta3 = 5.0f * v5;
            float Ta4 = Ta2 + Ta3;  float Ta5 = Ta4 + 140.0f; float Ta6 = Ta5 - u5;
            float Tbv = 0.2f * v5;  float Tbu = Tbv - u5; float Tdu = kaO * Tbu;
            float Tu1 = u5 + Tdu;   float Tud = Tu1 + 6.0f;
            float Tt7 = Ta6 + I5;   float Tv1 = fmaf(0.25f, Tt7, v5);
            bool Z5 = (Tv1 >= 30.0f);
            v5 = Z5 ? -65.0f : Tv1;  u5 = Z5 ? Tud : Tu1;

            // MN (I6 from current z5)
            float I6 = Z5 ? I6_1 : I6_0;
            float Ma1 = 0.04f * v6; float Ma2 = Ma1 * v6; float Ma3 = 5.0f * v6;
            float Ma4 = Ma2 + Ma3;  float Ma5 = Ma4 + 140.0f; float Ma6 = Ma5 - u6;
            float Mbv = 0.25f * v6; float Mbu = Mbv - u6; float Mdu = kaO * Mbu;
            float Mu1 = u6 + Mdu;   float Mud = Mu1 + 6.0f;
            float Mt7 = Ma6 + I6;   float Mv1 = fmaf(0.25f, Mt7, v6);
            bool Z6 = (Mv1 >= 30.0f);
            v6 = Z6 ? -65.0f : Mv1;  u6 = Z6 ? Mud : Mu1;

            zbL[j] = Z2 ? 1.0f : 0.0f;  vbL[j] = v2;
            zbE[j] = Z3 ? 1.0f : 0.0f;  vbE[j] = v3;
            zbI[j] = Z4 ? 1.0f : 0.0f;  vbI[j] = v4;
            zbT[j] = Z5 ? 1.0f : 0.0f;  vbT[j] = v5;
            zbM[j] = Z6 ? 1.0f : 0.0f;  vbM[j] = v6;

            z2p = Z2; z4p = Z4; z5p = Z5;
        }
        // batched flush by lane 0 (rows 16B-aligned at t; t % 4 == 0)
        if (tid == 0) {
            *(float4*)(p0 + t) = make_float4(zbL[0], zbL[1], zbL[2], zbL[3]);
            *(float4*)(p1 + t) = make_float4(zbE[0], zbE[1], zbE[2], zbE[3]);
            *(float4*)(p2 + t) = make_float4(zbI[0], zbI[1], zbI[2], zbI[3]);
            *(float4*)(p3 + t) = make_float4(zbT[0], zbT[1], zbT[2], zbT[3]);
            *(float4*)(p4 + t) = make_float4(zbM[0], zbM[1], zbM[2], zbM[3]);
            *(float4*)(q0 + t) = make_float4(vbL[0], vbL[1], vbL[2], vbL[3]);
            *(float4*)(q1 + t) = make_float4(vbE[0], vbE[1], vbE[2], vbE[3]);
            *(float4*)(q2 + t) = make_float4(vbI[0], vbI[1], vbI[2], vbI[3]);
            *(float4*)(q3 + t) = make_float4(vbT[0], vbT[1], vbT[2], vbT[3]);
            *(float4*)(q4 + t) = make_float4(vbM[0], vbM[1], vbM[2], vbM[3]);
        }
    }
    // tail (T not divisible by 4), only when no cycle was detected
    for (; t < T && t_det < 0; ++t) {
        float I2 = z4p ? (z2p ? I2_11 : I2_01) : (z2p ? I2_10 : I2_00);
        float La1 = 0.04f * v2; float La2 = La1 * v2; float La3 = 5.0f * v2;
        float La4 = La2 + La3;  float La5 = La4 + 140.0f; float La6 = La5 - u2;
        float Lbv = -0.075f * v2; float Lbu = Lbv - u2; float Ldu = kaL * Lbu;
        float Lu1 = u2 + Ldu;   float Lud = Lu1 + 6.0f;
        float Lt7 = La6 + I2;   float Lv1 = fmaf(0.25f, Lt7, v2);
        bool Z2 = (Lv1 >= 30.0f);
        v2 = Z2 ? -55.0f : Lv1;  u2 = Z2 ? Lud : Lu1;
        float I3 = Z2 ? I3_1 : I3_0;
        float Ea1 = 0.04f * v3; float Ea2 = Ea1 * v3; float Ea3 = 5.0f * v3;
        float Ea4 = Ea2 + Ea3;  float Ea5 = Ea4 + 140.0f; float Ea6 = Ea5 - u3;
        float Ebv = 0.25f * v3; float Ebu = Ebv - u3; float Edu = kaO * Ebu;
        float Eu1 = u3 + Edu;   float Eud = Eu1 + 0.05f;
        float Et7 = Ea6 + I3;   float Ev1 = fmaf(0.25f, Et7, v3);
        bool Z3 = (Ev1 >= 30.0f);
        v3 = Z3 ? -55.0f : Ev1;  u3 = Z3 ? Eud : Eu1;
        float I4 = Z3 ? I4_1 : I4_0;
        float Fa1 = 0.04f * v4; float Fa2 = Fa1 * v4; float Fa3 = 5.0f * v4;
        float Fa4 = Fa2 + Fa3;  float Fa5 = Fa4 + 140.0f; float Fa6 = Fa5 - u4;
        float Fbv = 0.25f * v4; float Fbu = Fbv - u4; float Fdu = kaO * Fbu;
        float Fu1 = u4 + Fdu;   float Fud = Fu1 + 6.0f;
        float Ft7 = Fa6 + I4;   float Fv1 = fmaf(0.25f, Ft7, v4);
        bool Z4 = (Fv1 >= 30.0f);
        v4 = Z4 ? -65.0f : Fv1;  u4 = Z4 ? Fud : Fu1;
        float I5 = z5p ? (Z3 ? I5_11 : I5_01) : (Z3 ? I5_10 : I5_00);
        float Ta1 = 0.04f * v5; float Ta2 = Ta1 * v5; float Ta3 = 5.0f * v5;
        float Ta4 = Ta2 + Ta3;  float Ta5 = Ta4 + 140.0f; float Ta6 = Ta5 - u5;
        float Tbv = 0.2f * v5;  float Tbu = Tbv - u5; float Tdu = kaO * Tbu;
        float Tu1 = u5 + Tdu;   float Tud = Tu1 + 6.0f;
        float Tt7 = Ta6 + I5;   float Tv1 = fmaf(0.25f, Tt7, v5);
        bool Z5 = (Tv1 >= 30.0f);
        v5 = Z5 ? -65.0f : Tv1;  u5 = Z5 ? Tud : Tu1;
        float I6 = Z5 ? I6_1 : I6_0;
        float Ma1 = 0.04f * v6; float Ma2 = Ma1 * v6; float Ma3 = 5.0f * v6;
        float Ma4 = Ma2 + Ma3;  float Ma5 = Ma4 + 140.0f; float Ma6 = Ma5 - u6;
        float Mbv = 0.25f * v6; float Mbu = Mbv - u6; float Mdu = kaO * Mbu;
        float Mu1 = u6 + Mdu;   float Mud = Mu1 + 6.0f;
        float Mt7 = Ma6 + I6;   float Mv1 = fmaf(0.25f, Mt7, v6);
        bool Z6 = (Mv1 >= 30.0f);
        v6 = Z6 ? -65.0f : Mv1;  u6 = Z6 ? Mud : Mu1;
        if (tid == 0) {
            p0[t] = Z2 ? 1.0f : 0.0f;  q0[t] = v2;
            p1[t] = Z3 ? 1.0f : 0.0f;  q1[t] = v3;
            p2[t] = Z4 ? 1.0f : 0.0f;  q2[t] = v4;
            p3[t] = Z5 ? 1.0f : 0.0f;  q3[t] = v5;
            p4[t] = Z6 ? 1.0f : 0.0f;  q4[t] = v6;
        }
        z2p = Z2; z4p = Z4; z5p = Z5;
    }

    // publish detection result (ws is re-poisoned before every call)
    if (tid == 0) {
        ws[0] = (t_det >= 0) ? 1 : 0;
        ws[1] = t_det;
        ws[2] = Pf;
    }
}

// Fills out[r, t] for t in [t_det, T) with the periodic continuation
// out[r, t_det - P + ((t - t_det) mod P)]. No-op when no cycle was found.
__global__ __launch_bounds__(256) void fill_cycle(float* __restrict__ out,
                                                  const int* __restrict__ ws,
                                                  int T) {
    if (ws[0] == 0) return;
    const int t0 = ws[1];
    const int P  = ws[2];
    const int r  = blockIdx.y;                    // 0..9 (row)
    const float* __restrict__ src = out + (size_t)r * T + (t0 - P);
    float* __restrict__ dst       = out + (size_t)r * T + t0;
    const int n = T - t0;
    for (int i = blockIdx.x * blockDim.x + threadIdx.x; i < n;
         i += gridDim.x * blockDim.x) {
        dst[i] = src[i % P];
    }
}

extern "C" void kernel_launch(void* const* d_in, const int* in_sizes, int n_in,
                              void* d_out, int out_size, void* d_ws, size_t ws_size,
                              hipStream_t stream) {
    const float* mat = (const float*)d_in[0];
    const float* w   = (const float*)d_in[1];
    // out_size = 2 outputs * 5 neurons * T  -> T = out_size/10
    int T = out_size / 10;
    net_sim<<<1, 256, 0, stream>>>(mat, w, (float*)d_out, (int*)d_ws, T);
    dim3 grid(40, 10, 1);
    fill_cycle<<<grid, 256, 0, stream>>>((float*)d_out, (const int*)d_ws, T);
}

// Round 10
// 308.131 us; speedup vs baseline: 1.6319x; 1.6319x over previous
//
#include <hip/hip_runtime.h>

// Exact-order float32 arithmetic: numpy/jax evaluate left-to-right with no
// FMA contraction. hipcc defaults to -ffp-contract=fast, which would change
// rounding -> possible spike-time shift -> large voltage absmax error.
#pragma clang fp contract(off)

// R23 = R18's skeleton (best verified: 256-260 us/dispatch, absmax 0.0)
// with pairs-adjacent lanes and select-don't-recompute via the PROVEN
// sel_mask (SGPR-pair cndmask) primitive.
// Cost model (calibrated R18/R22): time/step = max(2*N_instr, ~5*N_chain)
// cycles; R18 is latency-bound (N_chain~22). R23 removes ~3 chain VALU ops:
// post-ballot = SALU resolve -> sel_mask(v1,v1p,sp) -> sel_mask(.,c,fm)
// replacing R18's resolve -> cndmask Ia -> t7a -> v1a -> cmp -> cndmask.
// Lane map (pairs DPP-swappable via quad_perm[1,0,3,2], R16-proven):
//   0,1 = EBN  (z2-hyp 0/1)      true z3  = m bit(0+nz2)
//   2,3 = IFN  (z3-hyp 0/1)      true z4  = m bit(2+z3)
//   4,5 = TN   (z3-hyp 0/1)      true z5  = m bit(4+z3)   (z5p in prep)
//   6,7 = MN   (z5-hyp 0/1)      true z6  = m bit(6+nz5)
//   8   = LLBN (I2 from carries) true z2  = m bit 8
// Pair lanes hold bitwise-identical (v,u) (induction invariant: both always
// select the same final value), so the partner's candidate v1 IS the local
// recompute with the true I -> bitwise-identical outputs (absmax 0.0
// lineage R2..R22). u1/u1d are pair-identical -> u needs no partner select.
// take-partner mask sp: lane takes partner iff its hypothesis != true bit.
// fired mask fm: per-neuron resolved fire bit replicated to its lanes.
// Detection (rolling-40 anchor at block tops + Brent pow-2 fallback;
// 9-lane bitwise v/u ballots + carry equality), batched float4 flush
// (pair lanes store duplicate identical values - benign, R16-proven),
// fill_cycle: unchanged.

__device__ __forceinline__ float sel_mask(float a, float b, unsigned long long m) {
    float r;
    // D = m.bit[lane] ? S1 : S0   (VOP3 v_cndmask with SGPR-pair condition)
    asm("v_cndmask_b32 %0, %1, %2, %3" : "=v"(r) : "v"(a), "v"(b), "s"(m));
    return r;
}

// swap lanes within pairs (0<->1, 2<->3, ...): quad_perm [1,0,3,2] = 0xB1.
// Lane 8 reads inactive lane 9 -> 0 (bound_ctrl); never selected (sp bit8=0).
__device__ __forceinline__ float dpp_swap1(float x) {
    return __int_as_float(__builtin_amdgcn_update_dpp(
        0, __float_as_int(x), 0xB1, 0xF, 0xF, true));
}

__global__ __launch_bounds__(256) void net_sim(const float* __restrict__ mat,
                                               const float* __restrict__ w,
                                               float* __restrict__ out,
                                               int* __restrict__ ws,
                                               int T) {
    __shared__ double red[256];
    const int tid = threadIdx.x;

    // ---- z_plus = sum(input_mat * w0), f32 products accumulated in f64 ----
    const float w0 = w[0];
    double s = 0.0;
    for (int i = tid; i < 127 * 127; i += 256) {
        float p = mat[i] * w0;   // elementwise product rounded to f32 (as ref)
        s += (double)p;
    }
    red[tid] = s;
    __syncthreads();
    #pragma unroll
    for (int off = 128; off > 0; off >>= 1) {
        if (tid < off) red[tid] += red[tid + off];
        __syncthreads();
    }
    if (tid >= 9) return;   // 9 lanes of wave 0 continue; no more barriers

    const float z_plus = (float)red[0];

    const float w2 = w[2], w3 = w[3], w5 = w[5], w6 = w[6], w7 = w[7],
                w8 = w[8], w9 = w[9], w10 = w[10], w11 = w[11];
    const float zp_w1 = z_plus * w[1];
    const float zp_w4 = z_plus * w[4];

    // Validated constant-I set (R2..R22, absmax 0.0). z*w is exactly +0.0f
    // or w; x + (+0.0f) == x for the values involved.
    const float I2_00 = w2 * (zp_w1 - 0.0f) + w3 * 0.0f;   // (z2p, z4p)
    const float I2_10 = w2 * (zp_w1 - 0.0f) + w3 * 1.0f;
    const float I2_01 = w2 * (zp_w1 - w7)   + w3 * 0.0f;
    const float I2_11 = w2 * (zp_w1 - w7)   + w3 * 1.0f;
    const float I3_0  = zp_w4 + 0.0f * w5;
    const float I3_1  = zp_w4 + 1.0f * w5;
    const float I4_0  = 0.0f * w6;
    const float I4_1  = 1.0f * w6;
    const float I5_00 = w9 * (0.0f * w8) + w10 * 0.0f;     // (z3, z5p)
    const float I5_10 = w9 * (1.0f * w8) + w10 * 0.0f;
    const float I5_01 = w9 * (0.0f * w8) + w10 * 1.0f;
    const float I5_11 = w9 * (1.0f * w8) + w10 * 1.0f;
    const float I6_0  = 0.0f * w11;
    const float I6_1  = 1.0f * w11;

    // Lane map: 0,1=EBN  2,3=IFN  4,5=TN  6,7=MN  8=LLBN
    const int lane = tid;                 // 0..8
    const bool isL = (lane == 8);
    const int g = isL ? 0 : 1 + (lane >> 1);   // output row

    // per-lane params; ka = float(TAU*DT*a) computed in f64 like Python
    const float ka = isL ? (float)(0.25 * 0.1) : (float)(0.25 * 0.02);
    const float b  = isL ? -0.075f : (g == 3 ? 0.2f : 0.25f);
    const float c  = (isL || g == 1) ? -55.0f : -65.0f;
    const float d  = (g == 1) ? 0.05f : 6.0f;
    float v = isL ? -60.0f : (g == 3 ? -70.0f : -64.0f);
    float u = isL ? 4.5f   : (g == 3 ? -14.0f : -16.0f);

    // per-lane speculative I; _b differs from _a only for TN (z5p=1).
    // lane 8's value is a placeholder, overridden each step by fI2.
    const float Ib_a =
        lane == 0 ? I3_0 : lane == 1 ? I3_1 :
        lane == 2 ? I4_0 : lane == 3 ? I4_1 :
        lane == 4 ? I5_00 : lane == 5 ? I5_10 :
        lane == 6 ? I6_0 : lane == 7 ? I6_1 : I2_00;
    const float Ib_b = lane == 4 ? I5_01 : lane == 5 ? I5_11 : Ib_a;

    float* __restrict__ psp = out + g * T;           // spikes row
    float* __restrict__ pvv = out + 5 * T + g * T;   // volts row

    int z2 = 0, z4 = 0, z5 = 0;          // prev-step bits — uniform scalars
    unsigned long long z5m = 0ull;       // z5p broadcast mask for TN select

    // ---- cycle-detection: rolling-40 anchor + Brent pow-2 fallback ----
    float rav = 0.0f, rau = 0.0f; int raz2 = 0, raz4 = 0, raz5 = 0, ra_t = -1;
    float cav = 0.0f, cau = 0.0f; int caz2 = 0, caz4 = 0, caz5 = 0, ca_t = -1;
    int next_coarse = 8;
    int t_det = -1, Pf = 0;
    int blk5 = 0;   // t/8 mod 5; 0 <=> t % 40 == 0

    float zb[8], vb[8];

    int t = 0;
    for (; t + 8 <= T; t += 8) {
        // ---- block top: anchor compares / refresh (R9 semantics) ----
        if (blk5 == 0) {
            if (ra_t >= 0) {
                unsigned long long mv =
                    __ballot(__float_as_uint(v) == __float_as_uint(rav));
                unsigned long long mu =
                    __ballot(__float_as_uint(u) == __float_as_uint(rau));
                if (((mv & mu) & 0x1FFull) == 0x1FFull &&
                    z2 == raz2 && z4 == raz4 && z5 == raz5) {
                    t_det = t; Pf = t - ra_t;   // Pf == 40
                    break;
                }
            }
            if (t) { rav = v; rau = u; raz2 = z2; raz4 = z4; raz5 = z5; ra_t = t; }
        } else if (ca_t >= 0) {
            unsigned long long mv =
                __ballot(__float_as_uint(v) == __float_as_uint(cav));
            unsigned long long mu =
                __ballot(__float_as_uint(u) == __float_as_uint(cau));
            if (((mv & mu) & 0x1FFull) == 0x1FFull &&
                z2 == caz2 && z4 == caz4 && z5 == caz5) {
                t_det = t; Pf = t - ca_t;
                break;
            }
        }
        if (t == next_coarse) {
            cav = v; cau = u; caz2 = z2; caz4 = z4; caz5 = z5; ca_t = t;
            next_coarse <<= 1;
        }
        blk5 = (blk5 == 4) ? 0 : (blk5 + 1);

        #pragma unroll
        for (int j = 0; j < 8; ++j) {
            // speculative-I prep from prev-step bits (off critical path)
            float fI2 = z4 ? (z2 ? I2_11 : I2_01) : (z2 ? I2_10 : I2_00);
            float Ib = sel_mask(Ib_a, Ib_b, z5m);     // TN z5p variant
            Ib = sel_mask(Ib, fI2, 0x100ull);         // lane 8 <- true I2

            // izh head (I-independent)
            float t1 = 0.04f * v;
            float t2 = t1 * v;
            float t3 = 5.0f * v;
            float t4 = t2 + t3;
            float t5 = t4 + 140.0f;
            float t6 = t5 - u;
            float bv = b * v;
            float bvu = bv - u;
            float du = ka * bvu;
            float u1 = u + du;
            float u1d = u1 + d;

            // speculative tail; fmaf exact (R18-validated)
            float t7 = t6 + Ib;
            float v1 = fmaf(0.25f, t7, v);   // TAU*DT = 0.25 exactly
            float v1p = dpp_swap1(v1);       // partner's candidate (|| ballot)
            unsigned m = (unsigned)__ballot(v1 >= 30.0f);

            // uniform SALU resolve (R13-equivalent formulas, new bit layout)
            int nz2 = (int)((m >> 8) & 1u);          // LLBN fire
            int z3  = (int)((m >> nz2) & 1u);        // EBN fire
            int nz4 = (int)((m >> (2 + z3)) & 1u);   // IFN fire
            int nz5 = (int)((m >> (4 + z3)) & 1u);   // TN fire
            int nz6 = (int)((m >> (6 + nz5)) & 1u);  // MN fire
            unsigned long long sp =                  // take-partner mask
                  (nz2 ? 0x01ull : 0x02ull) | (z3 ? 0x14ull : 0x28ull)
                | (nz5 ? 0x40ull : 0x80ull);
            unsigned long long fm =                  // fired mask (per row)
                  (nz2 ? 0x100ull : 0ull) | (z3 ? 0x003ull : 0ull)
                | (nz4 ? 0x00Cull : 0ull) | (nz5 ? 0x030ull : 0ull)
                | (nz6 ? 0x0C0ull : 0ull);

            // final state: 2 chained cndmasks (select, don't recompute)
            float v1s = sel_mask(v1, v1p, sp);
            v = sel_mask(v1s, c, fm);
            u = sel_mask(u1, u1d, fm);       // u1/u1d pair-identical
            zb[j] = sel_mask(0.0f, 1.0f, fm);
            vb[j] = v;

            z2 = nz2; z4 = nz4; z5 = nz5;
            z5m = nz5 ? ~0ull : 0ull;
        }
        // batched flush (rows 16B-aligned at t; t % 8 == 0); pair lanes
        // store duplicate identical values — benign
        *(float4*)(psp)     = make_float4(zb[0], zb[1], zb[2], zb[3]);
        *(float4*)(psp + 4) = make_float4(zb[4], zb[5], zb[6], zb[7]);
        *(float4*)(pvv)     = make_float4(vb[0], vb[1], vb[2], vb[3]);
        *(float4*)(pvv + 4) = make_float4(vb[4], vb[5], vb[6], vb[7]);
        psp += 8;
        pvv += 8;
    }
    // tail (T not divisible by 8), only when no cycle was detected
    for (; t < T && t_det < 0; ++t) {
        float fI2 = z4 ? (z2 ? I2_11 : I2_01) : (z2 ? I2_10 : I2_00);
        float Ib = sel_mask(Ib_a, Ib_b, z5m);
        Ib = sel_mask(Ib, fI2, 0x100ull);
        float t1 = 0.04f * v;
        float t2 = t1 * v;
        float t3 = 5.0f * v;
        float t4 = t2 + t3;
        float t5 = t4 + 140.0f;
        float t6 = t5 - u;
        float bv = b * v;
        float bvu = bv - u;
        float du = ka * bvu;
        float u1 = u + du;
        float u1d = u1 + d;
        float t7 = t6 + Ib;
        float v1 = fmaf(0.25f, t7, v);
        float v1p = dpp_swap1(v1);
        unsigned m = (unsigned)__ballot(v1 >= 30.0f);
        int nz2 = (int)((m >> 8) & 1u);
        int z3  = (int)((m >> nz2) & 1u);
        int nz4 = (int)((m >> (2 + z3)) & 1u);
        int nz5 = (int)((m >> (4 + z3)) & 1u);
        int nz6 = (int)((m >> (6 + nz5)) & 1u);
        unsigned long long sp =
              (nz2 ? 0x01ull : 0x02ull) | (z3 ? 0x14ull : 0x28ull)
            | (nz5 ? 0x40ull : 0x80ull);
        unsigned long long fm =
              (nz2 ? 0x100ull : 0ull) | (z3 ? 0x003ull : 0ull)
            | (nz4 ? 0x00Cull : 0ull) | (nz5 ? 0x030ull : 0ull)
            | (nz6 ? 0x0C0ull : 0ull);
        float v1s = sel_mask(v1, v1p, sp);
        v = sel_mask(v1s, c, fm);
        u = sel_mask(u1, u1d, fm);
        psp[0] = sel_mask(0.0f, 1.0f, fm);
        pvv[0] = v;
        ++psp; ++pvv;
        z2 = nz2; z4 = nz4; z5 = nz5;
        z5m = nz5 ? ~0ull : 0ull;
    }

    // publish detection result (ws is re-poisoned before every call)
    if (lane == 0) {
        ws[0] = (t_det >= 0) ? 1 : 0;
        ws[1] = t_det;
        ws[2] = Pf;
    }
}

// Fills out[r, t] for t in [t_det, T) with the periodic continuation
// out[r, t_det - P + ((t - t_det) mod P)]. No-op when no cycle was found.
__global__ __launch_bounds__(256) void fill_cycle(float* __restrict__ out,
                                                  const int* __restrict__ ws,
                                                  int T) {
    if (ws[0] == 0) return;
    const int t0 = ws[1];
    const int P  = ws[2];
    const int r  = blockIdx.y;                    // 0..9 (row)
    const float* __restrict__ src = out + (size_t)r * T + (t0 - P);
    float* __restrict__ dst       = out + (size_t)r * T + t0;
    const int n = T - t0;
    for (int i = blockIdx.x * blockDim.x + threadIdx.x; i < n;
         i += gridDim.x * blockDim.x) {
        dst[i] = src[i % P];
    }
}

extern "C" void kernel_launch(void* const* d_in, const int* in_sizes, int n_in,
                              void* d_out, int out_size, void* d_ws, size_t ws_size,
                              hipStream_t stream) {
    const float* mat = (const float*)d_in[0];
    const float* w   = (const float*)d_in[1];
    // out_size = 2 outputs * 5 neurons * T  -> T = out_size/10
    int T = out_size / 10;
    net_sim<<<1, 256, 0, stream>>>(mat, w, (float*)d_out, (int*)d_ws, T);
    dim3 grid(40, 10, 1);
    fill_cycle<<<grid, 256, 0, stream>>>((float*)d_out, (const int*)d_ws, T);
}